// Round 3
// baseline (1353.082 us; speedup 1.0000x reference)
//
#include <hip/hip_runtime.h>
#include <hip/hip_bf16.h>
#include <math.h>

#define DIM   384
#define HEADS 8
#define HD    48
#define NTOK  32768   // 8 * 64 * 64
#define NWIN  512     // 8 images * 64 windows

typedef __attribute__((ext_vector_type(8))) short bf16x8;
typedef __attribute__((ext_vector_type(8))) unsigned short u16x8;
typedef __attribute__((ext_vector_type(4))) float f32x4;

__device__ __forceinline__ float bf2f(unsigned short u) {
    unsigned int v = ((unsigned int)u) << 16;
    return __uint_as_float(v);
}
__device__ __forceinline__ unsigned short f2bf(float f) {
    unsigned int x = __float_as_uint(f);
    unsigned int r = (x + 0x7fffu + ((x >> 16) & 1u)) >> 16;  // RNE
    return (unsigned short)r;
}

// token (window order) -> source pixel of x (accounting for roll by -SHIFT)
__device__ __forceinline__ void tok2src(int tok, int& b, int& hs, int& ws) {
    int bb  = tok >> 12;
    int win = (tok >> 6) & 63;
    int t   = tok & 63;
    int hi = win >> 3, wi = win & 7;
    int r  = t >> 3,  cc = t & 7;
    b  = bb;
    hs = (hi * 8 + r  + 4) & 63;
    ws = (wi * 8 + cc + 4) & 63;
}

// ------------- merged weight convert: 4 segments f32 [K][N] -> bf16 [N][K] --
__global__ __launch_bounds__(256) void k_wt4(const float* __restrict__ qkv_w,
                                             const float* __restrict__ proj_w,
                                             const float* __restrict__ w1,
                                             const float* __restrict__ w2,
                                             unsigned short* __restrict__ d0,
                                             unsigned short* __restrict__ d1,
                                             unsigned short* __restrict__ d2,
                                             unsigned short* __restrict__ d3) {
    int idx = blockIdx.x * 256 + threadIdx.x;
    const float* W; unsigned short* Wt; int K, N, loc;
    if (idx < 442368)       { W = qkv_w;  Wt = d0; K = 384;  N = 1152; loc = idx; }
    else if (idx < 589824)  { W = proj_w; Wt = d1; K = 384;  N = 384;  loc = idx - 442368; }
    else if (idx < 1179648) { W = w1;     Wt = d2; K = 384;  N = 1536; loc = idx - 589824; }
    else                    { W = w2;     Wt = d3; K = 1536; N = 384;  loc = idx - 1179648; }
    int n = loc / K, k = loc - n * K;
    Wt[loc] = f2bf(W[(size_t)k * N + n]);
}

// -------- gather + LayerNorm1, per (b, image-row hs), coalesced ------------
__global__ __launch_bounds__(256) void k_ln1(const float* __restrict__ x,
                                             const float* __restrict__ g,
                                             const float* __restrict__ bt,
                                             unsigned short* __restrict__ ln1) {
    int blk = blockIdx.x;           // b*64 + hs
    int b  = blk >> 6, hs = blk & 63;
    int t  = threadIdx.x;
    int w  = t & 63, cg = t >> 6;   // pixel, channel-group (4)
    const float* row = x + (size_t)b * DIM * 4096 + hs * 64;

    // phase A: coalesced read, per-pixel partial sums
    float sum = 0.f, sq = 0.f;
    for (int i = 0; i < 96; i++) {
        int c = i * 4 + cg;
        float v = row[(size_t)c * 4096 + w];
        sum += v; sq += v * v;
    }
    __shared__ float red[2][4][64];
    __shared__ float mean_s[64], rstd_s[64];
    red[0][cg][w] = sum; red[1][cg][w] = sq;
    __syncthreads();
    if (t < 64) {
        float s  = red[0][0][t] + red[0][1][t] + red[0][2][t] + red[0][3][t];
        float q2 = red[1][0][t] + red[1][1][t] + red[1][2][t] + red[1][3][t];
        float mean = s * (1.0f / DIM);
        float var  = q2 * (1.0f / DIM) - mean * mean;
        mean_s[t] = mean;
        rstd_s[t] = rsqrtf(var + 1e-5f);
    }
    __syncthreads();

    // output pixel for copy-out phase
    int wp = t >> 2, seg = t & 3;
    int hr = (hs + 60) & 63, wr = (wp + 60) & 63;
    int tok = ((b * 8 + (hr >> 3)) * 8 + (wr >> 3)) * 64 + (hr & 7) * 8 + (wr & 7);

    __shared__ __align__(16) unsigned short tile[64][72];
    for (int chunk = 0; chunk < 6; chunk++) {
        float mean = mean_s[w], rstd = rstd_s[w];
        #pragma unroll
        for (int it = 0; it < 16; it++) {
            int cl = it * 4 + cg;
            int c  = chunk * 64 + cl;
            float v = row[(size_t)c * 4096 + w];
            tile[w][cl] = f2bf((v - mean) * rstd * g[c] + bt[c]);
        }
        __syncthreads();
        u16x8 v0 = *(const u16x8*)&tile[wp][seg * 16];
        u16x8 v1 = *(const u16x8*)&tile[wp][seg * 16 + 8];
        unsigned short* op = ln1 + (size_t)tok * DIM + chunk * 64 + seg * 16;
        *(u16x8*)op = v0;
        *(u16x8*)(op + 8) = v1;
        __syncthreads();
    }
}

// ---------------- MFMA GEMM: C[M,N] = A[M,K](bf16) * Bt[N,K]^T(bf16) + bias
// 128x128 tile, 4 waves, 4x4 16x16x32 MFMA, BK=32, double-buffered LDS,
// XCD-aware block remap, LDS-staged bf16 epilogue.
// EPI: 0 bias->bf16; 1 bias+gelu->bf16; 2 bias+residual gather->f32; 3 bias->f32
template <int EPI>
__global__ __launch_bounds__(256) void k_gemm_mfma(
        const unsigned short* __restrict__ A,
        const unsigned short* __restrict__ Bt,
        const float* __restrict__ bias,
        void* __restrict__ Cout,
        const float* __restrict__ xres,
        int N, int K, int GX) {
    // smem[buf][0]=A-tile, smem[buf][1]=B-tile; 32 KB total; reused by epilogue
    __shared__ __align__(16) unsigned short smem[2][2][4096];
    int tid  = threadIdx.x;
    int lane = tid & 63;
    int wave = tid >> 6;
    int wm = wave >> 1, wn = wave & 1;
    int quad = lane >> 4, l15 = lane & 15;

    // XCD swizzle: all GX n-blocks of one m-row-block land on one XCD
    int l   = blockIdx.x;
    int xcd = l & 7;
    int r_  = l >> 3;
    int bx  = r_ % GX;
    int by  = (r_ / GX) * 8 + xcd;
    int m0 = by * 128, n0 = bx * 128;

    f32x4 acc[4][4] = {};

    auto stage = [&](int k0, int buf) {
        #pragma unroll
        for (int i = 0; i < 2; i++) {
            int c = wave + i * 4;       // 0..7
            int g = c & 3, j = c >> 2;  // kgroup, row-half
            const unsigned short* gpA = A + (size_t)(m0 + j * 64 + lane) * K + k0 + g * 8;
            __builtin_amdgcn_global_load_lds(
                (const __attribute__((address_space(1))) void*)gpA,
                (__attribute__((address_space(3))) void*)&smem[buf][0][(g * 128 + j * 64) * 8],
                16, 0, 0);
            const unsigned short* gpB = Bt + (size_t)(n0 + j * 64 + lane) * K + k0 + g * 8;
            __builtin_amdgcn_global_load_lds(
                (const __attribute__((address_space(1))) void*)gpB,
                (__attribute__((address_space(3))) void*)&smem[buf][1][(g * 128 + j * 64) * 8],
                16, 0, 0);
        }
    };

    int nk = K >> 5;
    stage(0, 0);
    for (int ik = 0; ik < nk; ik++) {
        __syncthreads();                       // drains prefetch into buf ik&1
        if (ik + 1 < nk) stage((ik + 1) << 5, (ik + 1) & 1);
        const unsigned short* Ab = smem[ik & 1][0];
        const unsigned short* Bb = smem[ik & 1][1];
        bf16x8 af[4], bfr[4];
        #pragma unroll
        for (int r = 0; r < 4; r++)
            af[r] = *(const bf16x8*)&Ab[(quad * 128 + wm * 64 + r * 16 + l15) * 8];
        #pragma unroll
        for (int r2 = 0; r2 < 4; r2++)
            bfr[r2] = *(const bf16x8*)&Bb[(quad * 128 + wn * 64 + r2 * 16 + l15) * 8];
        #pragma unroll
        for (int r = 0; r < 4; r++)
            #pragma unroll
            for (int r2 = 0; r2 < 4; r2++)
                acc[r][r2] = __builtin_amdgcn_mfma_f32_16x16x32_bf16(
                                 af[r], bfr[r2], acc[r][r2], 0, 0, 0);
    }

    float bn[4];
    #pragma unroll
    for (int r2 = 0; r2 < 4; r2++) bn[r2] = bias[n0 + wn * 64 + r2 * 16 + l15];

    if (EPI == 0 || EPI == 1) {
        // LDS-staged coalesced bf16 epilogue, two 64-row passes
        unsigned short* st = &smem[0][0][0];    // [64][136] ushort = 17408 B
        for (int p = 0; p < 2; p++) {
            __syncthreads();
            if (wm == p) {
                #pragma unroll
                for (int r = 0; r < 4; r++)
                    #pragma unroll
                    for (int reg = 0; reg < 4; reg++) {
                        int rowl = r * 16 + quad * 4 + reg;
                        #pragma unroll
                        for (int r2 = 0; r2 < 4; r2++) {
                            float v = acc[r][r2][reg] + bn[r2];
                            if (EPI == 1)
                                v = 0.5f * v * (1.0f + erff(v * 0.70710678118654752f));
                            st[rowl * 136 + wn * 64 + r2 * 16 + l15] = f2bf(v);
                        }
                    }
            }
            __syncthreads();
            #pragma unroll
            for (int s = 0; s < 4; s++) {
                int idx  = s * 256 + tid;
                int rowl = idx >> 4;
                int ch   = idx & 15;
                u16x8 v = *(const u16x8*)&st[rowl * 136 + ch * 8];
                *(u16x8*)((unsigned short*)Cout +
                          (size_t)(m0 + p * 64 + rowl) * N + n0 + ch * 8) = v;
            }
        }
    } else {
        #pragma unroll
        for (int r2 = 0; r2 < 4; r2++) {
            int n = n0 + wn * 64 + r2 * 16 + l15;
            #pragma unroll
            for (int r = 0; r < 4; r++) {
                #pragma unroll
                for (int reg = 0; reg < 4; reg++) {
                    int m = m0 + wm * 64 + r * 16 + quad * 4 + reg;
                    float v = acc[r][r2][reg] + bn[r2];
                    if (EPI == 2) {
                        int b, hs, ws_;
                        tok2src(m, b, hs, ws_);
                        v += xres[(((size_t)b * DIM + n) * 64 + hs) * 64 + ws_];
                    }
                    ((float*)Cout)[(size_t)m * N + n] = v;
                }
            }
        }
    }
}

// ---------------- attention per (window, head), vectorized ------------------
__global__ __launch_bounds__(64) void k_attn(const unsigned short* __restrict__ qkv,
                                             unsigned short* __restrict__ attn) {
    int win  = blockIdx.x >> 3;
    int head = blockIdx.x & 7;
    int t    = threadIdx.x;
    int tok0 = win * 64;

    __shared__ float Ks[64][52];
    __shared__ float Vs[64][52];

    const unsigned short* rowp = qkv + (size_t)(tok0 + t) * (3 * DIM) + head * HD;
    const float scale = 0.14433756729740643f;  // 48^-0.5
    float q[HD];
    #pragma unroll
    for (int i = 0; i < 6; i++) {
        u16x8 qv = *(const u16x8*)&rowp[i * 8];
        u16x8 kv = *(const u16x8*)&rowp[DIM + i * 8];
        u16x8 vv = *(const u16x8*)&rowp[2 * DIM + i * 8];
        #pragma unroll
        for (int j = 0; j < 8; j++) {
            q[i * 8 + j]       = bf2f(qv[j]) * scale;
            Ks[t][i * 8 + j]   = bf2f(kv[j]);
            Vs[t][i * 8 + j]   = bf2f(vv[j]);
        }
    }
    __syncthreads();

    float s[64];
    float mx = -1e30f;
    #pragma unroll
    for (int m = 0; m < 64; m++) {
        float acc = 0.f;
        #pragma unroll
        for (int d4 = 0; d4 < HD / 4; d4++) {
            float4 kk = *(const float4*)&Ks[m][d4 * 4];
            acc += q[d4 * 4 + 0] * kk.x + q[d4 * 4 + 1] * kk.y
                 + q[d4 * 4 + 2] * kk.z + q[d4 * 4 + 3] * kk.w;
        }
        s[m] = acc;
        mx = fmaxf(mx, acc);
    }
    float denom = 0.f;
    #pragma unroll
    for (int m = 0; m < 64; m++) {
        float e = __expf(s[m] - mx);
        s[m] = e;
        denom += e;
    }
    float inv = 1.0f / denom;
    float out[HD];
    #pragma unroll
    for (int d = 0; d < HD; d++) out[d] = 0.f;
    #pragma unroll
    for (int m = 0; m < 64; m++) {
        float p = s[m] * inv;
        #pragma unroll
        for (int d4 = 0; d4 < HD / 4; d4++) {
            float4 vv = *(const float4*)&Vs[m][d4 * 4];
            out[d4 * 4 + 0] += p * vv.x;
            out[d4 * 4 + 1] += p * vv.y;
            out[d4 * 4 + 2] += p * vv.z;
            out[d4 * 4 + 3] += p * vv.w;
        }
    }
    unsigned short* op = attn + (size_t)(tok0 + t) * DIM + head * HD;
    #pragma unroll
    for (int i = 0; i < 6; i++) {
        u16x8 ov;
        #pragma unroll
        for (int j = 0; j < 8; j++) ov[j] = f2bf(out[i * 8 + j]);
        *(u16x8*)&op[i * 8] = ov;
    }
}

// ---------------- LayerNorm2 over y (f32) -> ln2 (bf16) ----------
__global__ __launch_bounds__(64) void k_ln2(const float* __restrict__ y,
                                            const float* __restrict__ g,
                                            const float* __restrict__ bt,
                                            unsigned short* __restrict__ out) {
    int tok = blockIdx.x;
    int t   = threadIdx.x;
    const float* row = y + (size_t)tok * DIM;
    float v[6];
    float sum = 0.f, sq = 0.f;
    #pragma unroll
    for (int i = 0; i < 6; i++) {
        v[i] = row[i * 64 + t];
        sum += v[i]; sq += v[i] * v[i];
    }
    #pragma unroll
    for (int o = 32; o > 0; o >>= 1) {
        sum += __shfl_xor(sum, o, 64);
        sq  += __shfl_xor(sq, o, 64);
    }
    float mean = sum * (1.0f / DIM);
    float var  = sq * (1.0f / DIM) - mean * mean;
    float rstd = rsqrtf(var + 1e-5f);
    unsigned short* orow = out + (size_t)tok * DIM;
    #pragma unroll
    for (int i = 0; i < 6; i++) {
        int c = i * 64 + t;
        orow[c] = f2bf((v[i] - mean) * rstd * g[c] + bt[c]);
    }
}

// ---------------- un-permute + transpose to [B,C,H,W] ------------
__global__ __launch_bounds__(256) void k_out(const float* __restrict__ hbuf,
                                             float* __restrict__ out) {
    int bh = blockIdx.x;
    int b = bh >> 6, h = bh & 63;
    int t = threadIdx.x;
    __shared__ float T[64][193];
    int hh = (h + 60) & 63;
    int hi = hh >> 3, r = hh & 7;
    for (int half = 0; half < 2; half++) {
        int c0 = half * 192;
        for (int idx = t; idx < 64 * 192; idx += 256) {
            int w = idx / 192;
            int c = idx - w * 192;
            int ww = (w + 60) & 63;
            int wi = ww >> 3, cc2 = ww & 7;
            int tok = ((b * 8 + hi) * 8 + wi) * 64 + r * 8 + cc2;
            T[w][c] = hbuf[(size_t)tok * DIM + c0 + c];
        }
        __syncthreads();
        for (int idx = t; idx < 64 * 192; idx += 256) {
            int cc = idx >> 6;
            int w  = idx & 63;
            out[(((size_t)b * DIM + c0 + cc) * 64 + h) * 64 + w] = T[w][cc];
        }
        __syncthreads();
    }
}

extern "C" void kernel_launch(void* const* d_in, const int* in_sizes, int n_in,
                              void* d_out, int out_size, void* d_ws, size_t ws_size,
                              hipStream_t stream) {
    const float* x      = (const float*)d_in[0];
    const float* qkv_w  = (const float*)d_in[1];
    const float* qkv_b  = (const float*)d_in[2];
    const float* proj_w = (const float*)d_in[3];
    const float* proj_b = (const float*)d_in[4];
    const float* ln1_g  = (const float*)d_in[5];
    const float* ln1_b  = (const float*)d_in[6];
    const float* ln2_g  = (const float*)d_in[7];
    const float* ln2_b  = (const float*)d_in[8];
    const float* w1     = (const float*)d_in[9];
    const float* b1     = (const float*)d_in[10];
    const float* w2     = (const float*)d_in[11];
    const float* b2     = (const float*)d_in[12];

    char* ws = (char*)d_ws;
    // region map (bytes), peak 180,355,072:
    //   [0,        884736)     qkv_wt bf16 [1152][384]
    //   [884736,   1179648)    proj_wt bf16 [384][384]
    //   [1179648,  2359296)    w1t bf16 [1536][384]
    //   [2359296,  3538944)    w2t bf16 [384][1536]
    //   [4194304,  29360128)   ln1 bf16 [32768][384]   -- reused later as ln2
    //   [29360128, 104857600)  qkv bf16 [32768][1152]  -- reused later as mid
    //   [104857600,130023424)  attn bf16 [32768][384]  -- reused as mid(hi)
    //   [130023424,180355072)  y f32 [32768][384]      -- reused as hbuf
    unsigned short* qkv_wt  = (unsigned short*)(ws + 0);
    unsigned short* proj_wt = (unsigned short*)(ws + 884736);
    unsigned short* w1t     = (unsigned short*)(ws + 1179648);
    unsigned short* w2t     = (unsigned short*)(ws + 2359296);
    unsigned short* ln1     = (unsigned short*)(ws + 4194304);
    unsigned short* qkv     = (unsigned short*)(ws + 29360128);
    unsigned short* attn    = (unsigned short*)(ws + 104857600);
    float*          y       = (float*)(ws + 130023424);
    unsigned short* ln2     = ln1;
    unsigned short* mid     = qkv;      // [32768][1536] bf16
    float*          hbuf    = y;

    k_wt4<<<6912, 256, 0, stream>>>(qkv_w, proj_w, w1, w2, qkv_wt, proj_wt, w1t, w2t);
    k_ln1<<<512, 256, 0, stream>>>(x, ln1_g, ln1_b, ln1);
    k_gemm_mfma<0><<<9 * 256, 256, 0, stream>>>(ln1, qkv_wt, qkv_b, qkv, nullptr, 1152, 384, 9);
    k_attn<<<NWIN * HEADS, 64, 0, stream>>>(qkv, attn);
    k_gemm_mfma<2><<<3 * 256, 256, 0, stream>>>(attn, proj_wt, proj_b, y, x, 384, 384, 3);
    k_ln2<<<NTOK, 64, 0, stream>>>(y, ln2_g, ln2_b, ln2);
    k_gemm_mfma<1><<<12 * 256, 256, 0, stream>>>(ln2, w1t, b1, mid, nullptr, 1536, 384, 12);
    k_gemm_mfma<3><<<3 * 256, 256, 0, stream>>>(mid, w2t, b2, hbuf, nullptr, 384, 1536, 3);
    k_out<<<NWIN, 256, 0, stream>>>(hbuf, (float*)d_out);
}

// Round 4
// 689.639 us; speedup vs baseline: 1.9620x; 1.9620x over previous
//
#include <hip/hip_runtime.h>
#include <hip/hip_bf16.h>
#include <math.h>

#define DIM   384
#define HEADS 8
#define HD    48
#define NTOK  32768   // 8 * 64 * 64
#define NWIN  512     // 8 images * 64 windows

typedef __attribute__((ext_vector_type(8))) short bf16x8;
typedef __attribute__((ext_vector_type(8))) unsigned short u16x8;
typedef __attribute__((ext_vector_type(4))) float f32x4;

__device__ __forceinline__ float bf2f(unsigned short u) {
    unsigned int v = ((unsigned int)u) << 16;
    return __uint_as_float(v);
}
__device__ __forceinline__ unsigned short f2bf(float f) {
    unsigned int x = __float_as_uint(f);
    unsigned int r = (x + 0x7fffu + ((x >> 16) & 1u)) >> 16;  // RNE
    return (unsigned short)r;
}

// token (window order) -> source pixel of x (accounting for roll by -SHIFT)
__device__ __forceinline__ void tok2src(int tok, int& b, int& hs, int& ws) {
    int bb  = tok >> 12;
    int win = (tok >> 6) & 63;
    int t   = tok & 63;
    int hi = win >> 3, wi = win & 7;
    int r  = t >> 3,  cc = t & 7;
    b  = bb;
    hs = (hi * 8 + r  + 4) & 63;
    ws = (wi * 8 + cc + 4) & 63;
}

// ------------- merged weight convert: 4 segments f32 [K][N] -> bf16 [N][K] --
__global__ __launch_bounds__(256) void k_wt4(const float* __restrict__ qkv_w,
                                             const float* __restrict__ proj_w,
                                             const float* __restrict__ w1,
                                             const float* __restrict__ w2,
                                             unsigned short* __restrict__ d0,
                                             unsigned short* __restrict__ d1,
                                             unsigned short* __restrict__ d2,
                                             unsigned short* __restrict__ d3) {
    int idx = blockIdx.x * 256 + threadIdx.x;
    const float* W; unsigned short* Wt; int K, N, loc;
    if (idx < 442368)       { W = qkv_w;  Wt = d0; K = 384;  N = 1152; loc = idx; }
    else if (idx < 589824)  { W = proj_w; Wt = d1; K = 384;  N = 384;  loc = idx - 442368; }
    else if (idx < 1179648) { W = w1;     Wt = d2; K = 384;  N = 1536; loc = idx - 589824; }
    else                    { W = w2;     Wt = d3; K = 1536; N = 384;  loc = idx - 1179648; }
    int n = loc / K, k = loc - n * K;
    Wt[loc] = f2bf(W[(size_t)k * N + n]);
}

// -------- gather + LayerNorm1, per (b, image-row hs), coalesced ------------
__global__ __launch_bounds__(256) void k_ln1(const float* __restrict__ x,
                                             const float* __restrict__ g,
                                             const float* __restrict__ bt,
                                             unsigned short* __restrict__ ln1) {
    int blk = blockIdx.x;           // b*64 + hs
    int b  = blk >> 6, hs = blk & 63;
    int t  = threadIdx.x;
    int w  = t & 63, cg = t >> 6;   // pixel, channel-group (4)
    const float* row = x + (size_t)b * DIM * 4096 + hs * 64;

    float sum = 0.f, sq = 0.f;
    for (int i = 0; i < 96; i++) {
        int c = i * 4 + cg;
        float v = row[(size_t)c * 4096 + w];
        sum += v; sq += v * v;
    }
    __shared__ float red[2][4][64];
    __shared__ float mean_s[64], rstd_s[64];
    red[0][cg][w] = sum; red[1][cg][w] = sq;
    __syncthreads();
    if (t < 64) {
        float s  = red[0][0][t] + red[0][1][t] + red[0][2][t] + red[0][3][t];
        float q2 = red[1][0][t] + red[1][1][t] + red[1][2][t] + red[1][3][t];
        float mean = s * (1.0f / DIM);
        float var  = q2 * (1.0f / DIM) - mean * mean;
        mean_s[t] = mean;
        rstd_s[t] = rsqrtf(var + 1e-5f);
    }
    __syncthreads();

    int wp = t >> 2, seg = t & 3;
    int hr = (hs + 60) & 63, wr = (wp + 60) & 63;
    int tok = ((b * 8 + (hr >> 3)) * 8 + (wr >> 3)) * 64 + (hr & 7) * 8 + (wr & 7);

    __shared__ __align__(16) unsigned short tile[64][72];
    for (int chunk = 0; chunk < 6; chunk++) {
        float mean = mean_s[w], rstd = rstd_s[w];
        #pragma unroll
        for (int it = 0; it < 16; it++) {
            int cl = it * 4 + cg;
            int c  = chunk * 64 + cl;
            float v = row[(size_t)c * 4096 + w];
            tile[w][cl] = f2bf((v - mean) * rstd * g[c] + bt[c]);
        }
        __syncthreads();
        u16x8 v0 = *(const u16x8*)&tile[wp][seg * 16];
        u16x8 v1 = *(const u16x8*)&tile[wp][seg * 16 + 8];
        unsigned short* op = ln1 + (size_t)tok * DIM + chunk * 64 + seg * 16;
        *(u16x8*)op = v0;
        *(u16x8*)(op + 8) = v1;
        __syncthreads();
    }
}

// ---------------- MFMA GEMM: C[M,N] = A[M,K](bf16) * Bt[N,K]^T(bf16) + bias
// 128x128 tile, 4 waves, 4x4 16x16x32 MFMA, BK=32, double-buffered LDS,
// XCD-aware block remap, LDS-staged bf16 epilogue.
// EPI: 0 bias->bf16; 1 bias+gelu->bf16; 2 bias+residual gather->f32; 3 bias->f32
template <int EPI>
__global__ __launch_bounds__(256) void k_gemm_mfma(
        const unsigned short* __restrict__ A,
        const unsigned short* __restrict__ Bt,
        const float* __restrict__ bias,
        void* __restrict__ Cout,
        const float* __restrict__ xres,
        int N, int K, int GX) {
    __shared__ __align__(16) unsigned short smem[2][2][4096];
    int tid  = threadIdx.x;
    int lane = tid & 63;
    int wave = tid >> 6;
    int wm = wave >> 1, wn = wave & 1;
    int quad = lane >> 4, l15 = lane & 15;

    int l   = blockIdx.x;
    int xcd = l & 7;
    int r_  = l >> 3;
    int bx  = r_ % GX;
    int by  = (r_ / GX) * 8 + xcd;
    int m0 = by * 128, n0 = bx * 128;

    f32x4 acc[4][4] = {};

    auto stage = [&](int k0, int buf) {
        #pragma unroll
        for (int i = 0; i < 2; i++) {
            int c = wave + i * 4;       // 0..7
            int g = c & 3, j = c >> 2;  // kgroup, row-half
            const unsigned short* gpA = A + (size_t)(m0 + j * 64 + lane) * K + k0 + g * 8;
            __builtin_amdgcn_global_load_lds(
                (const __attribute__((address_space(1))) void*)gpA,
                (__attribute__((address_space(3))) void*)&smem[buf][0][(g * 128 + j * 64) * 8],
                16, 0, 0);
            const unsigned short* gpB = Bt + (size_t)(n0 + j * 64 + lane) * K + k0 + g * 8;
            __builtin_amdgcn_global_load_lds(
                (const __attribute__((address_space(1))) void*)gpB,
                (__attribute__((address_space(3))) void*)&smem[buf][1][(g * 128 + j * 64) * 8],
                16, 0, 0);
        }
    };

    int nk = K >> 5;
    stage(0, 0);
    for (int ik = 0; ik < nk; ik++) {
        __syncthreads();
        if (ik + 1 < nk) stage((ik + 1) << 5, (ik + 1) & 1);
        const unsigned short* Ab = smem[ik & 1][0];
        const unsigned short* Bb = smem[ik & 1][1];
        bf16x8 af[4], bfr[4];
        #pragma unroll
        for (int r = 0; r < 4; r++)
            af[r] = *(const bf16x8*)&Ab[(quad * 128 + wm * 64 + r * 16 + l15) * 8];
        #pragma unroll
        for (int r2 = 0; r2 < 4; r2++)
            bfr[r2] = *(const bf16x8*)&Bb[(quad * 128 + wn * 64 + r2 * 16 + l15) * 8];
        #pragma unroll
        for (int r = 0; r < 4; r++)
            #pragma unroll
            for (int r2 = 0; r2 < 4; r2++)
                acc[r][r2] = __builtin_amdgcn_mfma_f32_16x16x32_bf16(
                                 af[r], bfr[r2], acc[r][r2], 0, 0, 0);
    }

    float bn[4];
    #pragma unroll
    for (int r2 = 0; r2 < 4; r2++) bn[r2] = bias[n0 + wn * 64 + r2 * 16 + l15];

    if (EPI == 0 || EPI == 1) {
        unsigned short* st = &smem[0][0][0];    // [64][136] ushort
        for (int p = 0; p < 2; p++) {
            __syncthreads();
            if (wm == p) {
                #pragma unroll
                for (int r = 0; r < 4; r++)
                    #pragma unroll
                    for (int reg = 0; reg < 4; reg++) {
                        int rowl = r * 16 + quad * 4 + reg;
                        #pragma unroll
                        for (int r2 = 0; r2 < 4; r2++) {
                            float v = acc[r][r2][reg] + bn[r2];
                            if (EPI == 1)
                                v = 0.5f * v * (1.0f + erff(v * 0.70710678118654752f));
                            st[rowl * 136 + wn * 64 + r2 * 16 + l15] = f2bf(v);
                        }
                    }
            }
            __syncthreads();
            #pragma unroll
            for (int s = 0; s < 4; s++) {
                int idx  = s * 256 + tid;
                int rowl = idx >> 4;
                int ch   = idx & 15;
                u16x8 v = *(const u16x8*)&st[rowl * 136 + ch * 8];
                *(u16x8*)((unsigned short*)Cout +
                          (size_t)(m0 + p * 64 + rowl) * N + n0 + ch * 8) = v;
            }
        }
    } else {
        #pragma unroll
        for (int r2 = 0; r2 < 4; r2++) {
            int n = n0 + wn * 64 + r2 * 16 + l15;
            #pragma unroll
            for (int r = 0; r < 4; r++) {
                #pragma unroll
                for (int reg = 0; reg < 4; reg++) {
                    int m = m0 + wm * 64 + r * 16 + quad * 4 + reg;
                    float v = acc[r][r2][reg] + bn[r2];
                    if (EPI == 2) {
                        int b, hs, ws_;
                        tok2src(m, b, hs, ws_);
                        v += xres[(((size_t)b * DIM + n) * 64 + hs) * 64 + ws_];
                    }
                    ((float*)Cout)[(size_t)m * N + n] = v;
                }
            }
        }
    }
}

// ---------------- attention per (window, head) — round-2 proven version -----
__global__ __launch_bounds__(64) void k_attn(const unsigned short* __restrict__ qkv,
                                             unsigned short* __restrict__ attn) {
    int win  = blockIdx.x >> 3;
    int head = blockIdx.x & 7;
    int t    = threadIdx.x;
    int tok0 = win * 64;

    __shared__ float Ks[64][52];
    __shared__ float Vs[64][52];

    const unsigned short* rowp = qkv + (size_t)(tok0 + t) * (3 * DIM);
    #pragma unroll
    for (int d = 0; d < HD; d++) {
        Ks[t][d] = bf2f(rowp[DIM + head * HD + d]);
        Vs[t][d] = bf2f(rowp[2 * DIM + head * HD + d]);
    }
    const float scale = 0.14433756729740643f;  // 48^-0.5
    float q[HD];
    #pragma unroll
    for (int d = 0; d < HD; d++) q[d] = bf2f(rowp[head * HD + d]) * scale;
    __syncthreads();

    float s[64];
    float mx = -1e30f;
    #pragma unroll
    for (int m = 0; m < 64; m++) {
        float acc = 0.f;
        #pragma unroll
        for (int d4 = 0; d4 < HD / 4; d4++) {
            float4 kk = *(const float4*)&Ks[m][d4 * 4];
            acc += q[d4 * 4 + 0] * kk.x + q[d4 * 4 + 1] * kk.y
                 + q[d4 * 4 + 2] * kk.z + q[d4 * 4 + 3] * kk.w;
        }
        s[m] = acc;
        mx = fmaxf(mx, acc);
    }
    float denom = 0.f;
    #pragma unroll
    for (int m = 0; m < 64; m++) {
        float e = __expf(s[m] - mx);
        s[m] = e;
        denom += e;
    }
    float inv = 1.0f / denom;
    float out[HD];
    #pragma unroll
    for (int d = 0; d < HD; d++) out[d] = 0.f;
    #pragma unroll
    for (int m = 0; m < 64; m++) {
        float p = s[m] * inv;
        #pragma unroll
        for (int d4 = 0; d4 < HD / 4; d4++) {
            float4 vv = *(const float4*)&Vs[m][d4 * 4];
            out[d4 * 4 + 0] += p * vv.x;
            out[d4 * 4 + 1] += p * vv.y;
            out[d4 * 4 + 2] += p * vv.z;
            out[d4 * 4 + 3] += p * vv.w;
        }
    }
    unsigned short* op = attn + (size_t)(tok0 + t) * DIM + head * HD;
    #pragma unroll
    for (int d = 0; d < HD; d++) op[d] = f2bf(out[d]);
}

// ---------------- LayerNorm2 over y (f32) -> ln2 (bf16) ----------
__global__ __launch_bounds__(64) void k_ln2(const float* __restrict__ y,
                                            const float* __restrict__ g,
                                            const float* __restrict__ bt,
                                            unsigned short* __restrict__ out) {
    int tok = blockIdx.x;
    int t   = threadIdx.x;
    const float* row = y + (size_t)tok * DIM;
    float v[6];
    float sum = 0.f, sq = 0.f;
    #pragma unroll
    for (int i = 0; i < 6; i++) {
        v[i] = row[i * 64 + t];
        sum += v[i]; sq += v[i] * v[i];
    }
    #pragma unroll
    for (int o = 32; o > 0; o >>= 1) {
        sum += __shfl_xor(sum, o, 64);
        sq  += __shfl_xor(sq, o, 64);
    }
    float mean = sum * (1.0f / DIM);
    float var  = sq * (1.0f / DIM) - mean * mean;
    float rstd = rsqrtf(var + 1e-5f);
    unsigned short* orow = out + (size_t)tok * DIM;
    #pragma unroll
    for (int i = 0; i < 6; i++) {
        int c = i * 64 + t;
        orow[c] = f2bf((v[i] - mean) * rstd * g[c] + bt[c]);
    }
}

// ---------------- un-permute + transpose to [B,C,H,W] ------------
__global__ __launch_bounds__(256) void k_out(const float* __restrict__ hbuf,
                                             float* __restrict__ out) {
    int bh = blockIdx.x;
    int b = bh >> 6, h = bh & 63;
    int t = threadIdx.x;
    __shared__ float T[64][193];
    int hh = (h + 60) & 63;
    int hi = hh >> 3, r = hh & 7;
    for (int half = 0; half < 2; half++) {
        int c0 = half * 192;
        for (int idx = t; idx < 64 * 192; idx += 256) {
            int w = idx / 192;
            int c = idx - w * 192;
            int ww = (w + 60) & 63;
            int wi = ww >> 3, cc2 = ww & 7;
            int tok = ((b * 8 + hi) * 8 + wi) * 64 + r * 8 + cc2;
            T[w][c] = hbuf[(size_t)tok * DIM + c0 + c];
        }
        __syncthreads();
        for (int idx = t; idx < 64 * 192; idx += 256) {
            int cc = idx >> 6;
            int w  = idx & 63;
            out[(((size_t)b * DIM + c0 + cc) * 64 + h) * 64 + w] = T[w][cc];
        }
        __syncthreads();
    }
}

extern "C" void kernel_launch(void* const* d_in, const int* in_sizes, int n_in,
                              void* d_out, int out_size, void* d_ws, size_t ws_size,
                              hipStream_t stream) {
    const float* x      = (const float*)d_in[0];
    const float* qkv_w  = (const float*)d_in[1];
    const float* qkv_b  = (const float*)d_in[2];
    const float* proj_w = (const float*)d_in[3];
    const float* proj_b = (const float*)d_in[4];
    const float* ln1_g  = (const float*)d_in[5];
    const float* ln1_b  = (const float*)d_in[6];
    const float* ln2_g  = (const float*)d_in[7];
    const float* ln2_b  = (const float*)d_in[8];
    const float* w1     = (const float*)d_in[9];
    const float* b1     = (const float*)d_in[10];
    const float* w2     = (const float*)d_in[11];
    const float* b2     = (const float*)d_in[12];

    char* ws = (char*)d_ws;
    unsigned short* qkv_wt  = (unsigned short*)(ws + 0);
    unsigned short* proj_wt = (unsigned short*)(ws + 884736);
    unsigned short* w1t     = (unsigned short*)(ws + 1179648);
    unsigned short* w2t     = (unsigned short*)(ws + 2359296);
    unsigned short* ln1     = (unsigned short*)(ws + 4194304);
    unsigned short* qkv     = (unsigned short*)(ws + 29360128);
    unsigned short* attn    = (unsigned short*)(ws + 104857600);
    float*          y       = (float*)(ws + 130023424);
    unsigned short* ln2     = ln1;
    unsigned short* mid     = qkv;      // [32768][1536] bf16
    float*          hbuf    = y;

    k_wt4<<<6912, 256, 0, stream>>>(qkv_w, proj_w, w1, w2, qkv_wt, proj_wt, w1t, w2t);
    k_ln1<<<512, 256, 0, stream>>>(x, ln1_g, ln1_b, ln1);
    k_gemm_mfma<0><<<9 * 256, 256, 0, stream>>>(ln1, qkv_wt, qkv_b, qkv, nullptr, 1152, 384, 9);
    k_attn<<<NWIN * HEADS, 64, 0, stream>>>(qkv, attn);
    k_gemm_mfma<2><<<3 * 256, 256, 0, stream>>>(attn, proj_wt, proj_b, y, x, 384, 384, 3);
    k_ln2<<<NTOK, 64, 0, stream>>>(y, ln2_g, ln2_b, ln2);
    k_gemm_mfma<1><<<12 * 256, 256, 0, stream>>>(ln2, w1t, b1, mid, nullptr, 1536, 384, 12);
    k_gemm_mfma<3><<<3 * 256, 256, 0, stream>>>(mid, w2t, b2, hbuf, nullptr, 384, 1536, 3);
    k_out<<<NWIN, 256, 0, stream>>>(hbuf, (float*)d_out);
}